// Round 1
// baseline (631.065 us; speedup 1.0000x reference)
//
#include <hip/hip_runtime.h>

#define TT 128
#define BB 64
#define NIN 1024
#define NOUT 2048
#define MR (TT*BB)   // 8192 rows (T*B)

typedef unsigned short u16;
typedef __attribute__((ext_vector_type(8))) __bf16 bf16x8;
typedef __attribute__((ext_vector_type(4))) float f32x4;
typedef __attribute__((ext_vector_type(4))) unsigned short u16x4;

static __device__ __forceinline__ u16 f2bf(float f) {
    union { float f; unsigned u; } v; v.f = f;
    unsigned r = v.u + 0x7fffu + ((v.u >> 16) & 1u);  // RNE
    return (u16)(r >> 16);
}
static __device__ __forceinline__ float bf2f(u16 x) {
    union { unsigned u; float f; } v; v.u = ((unsigned)x) << 16;
    return v.f;
}

// ---- f32 -> bf16 convert (vectorized) ----
__global__ void k_cvt(const float* __restrict__ s, u16* __restrict__ d, int n4) {
    int i = blockIdx.x * blockDim.x + threadIdx.x;
    int st = gridDim.x * blockDim.x;
    for (; i < n4; i += st) {
        float4 v = ((const float4*)s)[i];
        u16x4 o;
        o.x = f2bf(v.x); o.y = f2bf(v.y); o.z = f2bf(v.z); o.w = f2bf(v.w);
        ((u16x4*)d)[i] = o;
    }
}

// ---- f32 [R][C] -> bf16 [C][R] transpose ----
__global__ void k_transpose(const float* __restrict__ s, u16* __restrict__ d, int R, int C) {
    __shared__ float tile[32][33];
    int c0 = blockIdx.x * 32, r0 = blockIdx.y * 32;
    int tx = threadIdx.x, ty = threadIdx.y;  // block (32,8)
    #pragma unroll
    for (int i = 0; i < 32; i += 8)
        tile[ty + i][tx] = s[(size_t)(r0 + ty + i) * C + c0 + tx];
    __syncthreads();
    #pragma unroll
    for (int i = 0; i < 32; i += 8)
        d[(size_t)(c0 + ty + i) * R + r0 + tx] = f2bf(tile[tx][ty + i]);
}

// ---- pack biases for the 4-gate fused GEMM: [xp=0, f=bf, r=br, cx=bcx] ----
__global__ void k_bias_pack(const float* __restrict__ bf_, const float* __restrict__ br_,
                            const float* __restrict__ bcx_, float* __restrict__ ball) {
    int i = blockIdx.x * 256 + threadIdx.x;  // 0..8191
    int g = i >> 11, n = i & 2047;
    float v = 0.f;
    if (g == 1) v = bf_[n];
    else if (g == 2) v = br_[n];
    else if (g == 3) v = bcx_[n];
    ball[i] = v;
}

// ---- bf16 GEMM, m97 structure: 128x128 tile, BK=32, 4 waves, 4x4 16x16x32 frags ----
// A [M][K] bf16 row-major, BT [N][K] bf16 row-major (B transposed).
// gateMode: N==4*2048 concatenated gates; sigmoid on groups 1,2; output [g][M][2048].
#define GLL16(SRC, DST) __builtin_amdgcn_global_load_lds( \
    (const __attribute__((address_space(1))) void*)(SRC), \
    (__attribute__((address_space(3))) void*)(DST), 16, 0, 0)

__global__ __launch_bounds__(256) void k_gemm(
    const u16* __restrict__ A, const u16* __restrict__ BT,
    const float* __restrict__ bias, u16* __restrict__ outh, float* __restrict__ outf,
    int M, int N, int K, int gateMode)
{
    __shared__ __align__(16) u16 As[128 * 32];
    __shared__ __align__(16) u16 Bs[128 * 32];

    const int tid = threadIdx.x;
    const int w = tid >> 6, lane = tid & 63;
    const int wr = w >> 1, wc = w & 1;
    const int lr = lane & 15, kq = lane >> 4;
    const int m0 = blockIdx.y * 128, n0 = blockIdx.x * 128;

    // staging: 512 chunks of 16B per tile; thread t handles chunks t and t+256.
    const int ca = tid, cb = tid + 256;
    const u16* aS0 = A + (size_t)(m0 + (ca >> 2)) * K + (ca & 3) * 8;
    const u16* aS1 = A + (size_t)(m0 + (cb >> 2)) * K + (cb & 3) * 8;
    const u16* bS0 = BT + (size_t)(n0 + (ca >> 2)) * K + (ca & 3) * 8;
    const u16* bS1 = BT + (size_t)(n0 + (cb >> 2)) * K + (cb & 3) * 8;
    u16* aD0 = &As[(w * 64) * 8];         // wave-uniform LDS base; HW adds lane*16B
    u16* aD1 = &As[(256 + w * 64) * 8];
    u16* bD0 = &Bs[(w * 64) * 8];
    u16* bD1 = &Bs[(256 + w * 64) * 8];

    f32x4 acc[4][4] = {};

    for (int kt = 0; kt < K; kt += 32) {
        GLL16(aS0 + kt, aD0);
        GLL16(aS1 + kt, aD1);
        GLL16(bS0 + kt, bD0);
        GLL16(bS1 + kt, bD1);
        __syncthreads();  // compiler drains vmcnt before barrier

        bf16x8 af[4], bfr[4];
        #pragma unroll
        for (int i = 0; i < 4; ++i)
            af[i] = *(const bf16x8*)&As[(wr * 64 + i * 16 + lr) * 32 + kq * 8];
        #pragma unroll
        for (int j = 0; j < 4; ++j)
            bfr[j] = *(const bf16x8*)&Bs[(wc * 64 + j * 16 + lr) * 32 + kq * 8];
        #pragma unroll
        for (int i = 0; i < 4; ++i)
            #pragma unroll
            for (int j = 0; j < 4; ++j)
                acc[i][j] = __builtin_amdgcn_mfma_f32_16x16x32_bf16(af[i], bfr[j], acc[i][j], 0, 0, 0);
        __syncthreads();
    }

    // epilogue: C/D lane map (verified m89/m91): col = lane&15, row = (lane>>4)*4 + reg
    const size_t GM = (size_t)M * 2048;
    #pragma unroll
    for (int i = 0; i < 4; ++i) {
        int r0 = m0 + wr * 64 + i * 16 + kq * 4;
        #pragma unroll
        for (int j = 0; j < 4; ++j) {
            int gc = n0 + wc * 64 + j * 16 + lr;
            float bv = bias ? bias[gc] : 0.f;
            int g = gc >> 11;
            bool sig = gateMode && (g == 1 || g == 2);
            #pragma unroll
            for (int q = 0; q < 4; ++q) {
                float v = acc[i][j][q] + bv;
                if (sig) v = 1.f / (1.f + __expf(-v));
                size_t off = gateMode
                    ? (size_t)g * GM + (size_t)(r0 + q) * 2048 + (size_t)(gc & 2047)
                    : (size_t)(r0 + q) * (size_t)N + (size_t)gc;
                if (outh) outh[off] = f2bf(v);
                if (outf) outf[off] = v;
            }
        }
    }
}

// ---- SRU recurrence + output: one thread per (b,n) chain ----
// G = [4][MR][2048] bf16: xp, f(post-sigmoid), r(post-sigmoid), cx
__global__ void k_scan(const u16* __restrict__ G, const float* __restrict__ c0,
                       u16* __restrict__ hb, float* __restrict__ hf,
                       float* __restrict__ cout)
{
    int idx = blockIdx.x * 256 + threadIdx.x;  // 0..BB*NOUT-1
    int b = idx >> 11, n = idx & 2047;
    float c = c0[idx];
    const size_t GM = (size_t)MR * 2048;
    for (int t = 0; t < TT; ++t) {
        size_t p = ((size_t)(t * BB + b) << 11) + (size_t)n;
        float xp = bf2f(G[p]);
        float f  = bf2f(G[GM + p]);
        float r  = bf2f(G[2 * GM + p]);
        float cx = bf2f(G[3 * GM + p]);
        c = f * c + (1.f - f) * xp;
        float h = r * tanhf(c) + (1.f - r) * cx;
        if (hb) hb[p] = f2bf(h);
        if (hf) hf[p] = h;
    }
    if (cout) cout[idx] = c;
}

extern "C" void kernel_launch(void* const* d_in, const int* in_sizes, int n_in,
                              void* d_out, int out_size, void* d_ws, size_t ws_size,
                              hipStream_t stream)
{
    const float* xt  = (const float*)d_in[0];
    const float* ctf = (const float*)d_in[1];
    const float* Wx  = (const float*)d_in[2];
    const float* Wf  = (const float*)d_in[3];
    const float* bfp = (const float*)d_in[4];
    const float* Wr  = (const float*)d_in[5];
    const float* brp = (const float*)d_in[6];
    const float* Wcx = (const float*)d_in[7];
    const float* bcx = (const float*)d_in[8];
    const float* Wcl = (const float*)d_in[9];
    const float* bcl = (const float*)d_in[10];
    float* out = (float*)d_out;

    char* ws = (char*)d_ws;
    u16* x0 = (u16*)ws;       ws += (size_t)MR * NIN * 2;        // 16.8 MB  x (layer1 in, bf16)
    u16* x2 = (u16*)ws;       ws += (size_t)MR * NIN * 2;        // 16.8 MB  x (layer2 in, bf16)
    u16* h1 = (u16*)ws;       ws += (size_t)MR * NOUT * 2;       // 33.6 MB  layer1 h (bf16)
    u16* WTall = (u16*)ws;    ws += (size_t)4 * NOUT * NIN * 2;  // 16.8 MB  [xp,f,r,cx] W^T bf16
    u16* WclT = (u16*)ws;     ws += (size_t)NIN * NOUT * 2;      //  4.2 MB  Wcl^T bf16
    float* ball = (float*)ws; ws += (size_t)4 * NOUT * 4;        //  32 KB   packed biases
    u16* G = (u16*)ws;        ws += (size_t)4 * MR * NOUT * 2;   // 134 MB   gates

    dim3 tb(32, 8);
    // conversions / transposes (per-call; ~20 us total)
    k_cvt<<<2048, 256, 0, stream>>>(xt, x0, (MR * NIN) / 4);
    k_transpose<<<dim3(NOUT / 32, NIN / 32), tb, 0, stream>>>(Wx,  WTall + 0 * (size_t)NOUT * NIN, NIN, NOUT);
    k_transpose<<<dim3(NOUT / 32, NIN / 32), tb, 0, stream>>>(Wf,  WTall + 1 * (size_t)NOUT * NIN, NIN, NOUT);
    k_transpose<<<dim3(NOUT / 32, NIN / 32), tb, 0, stream>>>(Wr,  WTall + 2 * (size_t)NOUT * NIN, NIN, NOUT);
    k_transpose<<<dim3(NOUT / 32, NIN / 32), tb, 0, stream>>>(Wcx, WTall + 3 * (size_t)NOUT * NIN, NIN, NOUT);
    k_transpose<<<dim3(NIN / 32, NOUT / 32), tb, 0, stream>>>(Wcl, WclT, NOUT, NIN);
    k_bias_pack<<<32, 256, 0, stream>>>(bfp, brp, bcx, ball);

    // layer 1: fused 4-gate GEMM (N = 4*2048), scan
    k_gemm<<<dim3(4 * NOUT / 128, MR / 128), 256, 0, stream>>>(
        x0, WTall, ball, G, (float*)nullptr, MR, 4 * NOUT, NIN, 1);
    k_scan<<<(BB * NOUT) / 256, 256, 0, stream>>>(
        G, ctf, h1, (float*)nullptr, (float*)nullptr);

    // inter-layer projection: x2 = h1 @ Wcl + bcl   (M=8192, N=1024, K=2048)
    k_gemm<<<dim3(NIN / 128, MR / 128), 256, 0, stream>>>(
        h1, WclT, bcl, x2, (float*)nullptr, MR, NIN, NOUT, 0);

    // layer 2: gates + scan -> d_out (h2 f32) + c_last
    k_gemm<<<dim3(4 * NOUT / 128, MR / 128), 256, 0, stream>>>(
        x2, WTall, ball, G, (float*)nullptr, MR, 4 * NOUT, NIN, 1);
    k_scan<<<(BB * NOUT) / 256, 256, 0, stream>>>(
        G, ctf + (size_t)BB * NOUT, (u16*)nullptr, out, out + (size_t)MR * NOUT);
}

// Round 2
// 613.246 us; speedup vs baseline: 1.0291x; 1.0291x over previous
//
#include <hip/hip_runtime.h>

#define TT 128
#define BB 64
#define NIN 1024
#define NOUT 2048
#define MR (TT*BB)   // 8192 rows (T*B)

typedef unsigned short u16;
typedef __attribute__((ext_vector_type(8))) __bf16 bf16x8;
typedef __attribute__((ext_vector_type(4))) float f32x4;
typedef __attribute__((ext_vector_type(4))) unsigned short u16x4;

static __device__ __forceinline__ u16 f2bf(float f) {
    union { float f; unsigned u; } v; v.f = f;
    unsigned r = v.u + 0x7fffu + ((v.u >> 16) & 1u);  // RNE
    return (u16)(r >> 16);
}
static __device__ __forceinline__ float bf2f(u16 x) {
    union { unsigned u; float f; } v; v.u = ((unsigned)x) << 16;
    return v.f;
}

__global__ void k_cvt(const float* __restrict__ s, u16* __restrict__ d, int n4) {
    int i = blockIdx.x * blockDim.x + threadIdx.x;
    int st = gridDim.x * blockDim.x;
    for (; i < n4; i += st) {
        float4 v = ((const float4*)s)[i];
        u16x4 o;
        o.x = f2bf(v.x); o.y = f2bf(v.y); o.z = f2bf(v.z); o.w = f2bf(v.w);
        ((u16x4*)d)[i] = o;
    }
}

__global__ void k_transpose(const float* __restrict__ s, u16* __restrict__ d, int R, int C) {
    __shared__ float tile[32][33];
    int c0 = blockIdx.x * 32, r0 = blockIdx.y * 32;
    int tx = threadIdx.x, ty = threadIdx.y;  // block (32,8)
    #pragma unroll
    for (int i = 0; i < 32; i += 8)
        tile[ty + i][tx] = s[(size_t)(r0 + ty + i) * C + c0 + tx];
    __syncthreads();
    #pragma unroll
    for (int i = 0; i < 32; i += 8)
        d[(size_t)(c0 + ty + i) * R + r0 + tx] = f2bf(tile[tx][ty + i]);
}

__global__ void k_bias_pack(const float* __restrict__ bf_, const float* __restrict__ br_,
                            const float* __restrict__ bcx_, float* __restrict__ ball) {
    int i = blockIdx.x * 256 + threadIdx.x;  // 0..8191
    int g = i >> 11, n = i & 2047;
    float v = 0.f;
    if (g == 1) v = bf_[n];
    else if (g == 2) v = br_[n];
    else if (g == 3) v = bcx_[n];
    ball[i] = v;
}

#define GLL16(SRC, DST) __builtin_amdgcn_global_load_lds( \
    (const __attribute__((address_space(1))) void*)(SRC), \
    (__attribute__((address_space(3))) void*)(DST), 16, 0, 0)
#define SBAR() __builtin_amdgcn_s_barrier()
#define SCHED0() __builtin_amdgcn_sched_barrier(0)

// 256x256 tile, BK=32, 8 waves (2Mx4N), 4-deep LDS ring (128 KiB), counted vmcnt.
// LDS per buffer: A then B, each stored as chunk(kslot q, row) = q*256+row of 16B
// (column-major in 16B units -> conflict-free ds_read_b128 fragment reads).
// Staged via per-lane-permuted global source addresses, linear gll dest (rule 21).
__global__ __launch_bounds__(512) void k_gemm256(
    const u16* __restrict__ A, const u16* __restrict__ BT,
    const float* __restrict__ bias, u16* __restrict__ out,
    int M, int N, int K, int gateMode)
{
    __shared__ __align__(16) u16 L[65536];  // 4 bufs x (A 16KB + B 16KB) = 128 KiB

    const int tid = threadIdx.x;
    const int w = tid >> 6, lane = tid & 63;
    const int wr = w >> 2, wc = w & 3;       // wave -> (128-row, 64-col) sub-tile
    const int lr = lane & 15, kq = lane >> 4;
    const int m0 = blockIdx.y * 256, n0 = blockIdx.x * 256;
    const int nk = K >> 5;

    // staging: chunk c = q*256 + row; thread t covers chunks t and t+512
    const int srow = tid & 255, sq = tid >> 8;
    const u16* aS = A + (size_t)(m0 + srow) * K + sq * 8;
    const u16* bS = BT + (size_t)(n0 + srow) * K + sq * 8;
    const int dA0 = w * 512, dA1 = 4096 + w * 512;     // wave-uniform LDS elem offsets
    const int dB0 = 8192 + w * 512, dB1 = 12288 + w * 512;

    // fragment read bases (elem): A frag i at +i*128; B frag j at +j*128
    const int rdA = kq * 2048 + (wr * 128 + lr) * 8;
    const int rdB = 8192 + kq * 2048 + (wc * 64 + lr) * 8;

    f32x4 acc[8][4] = {};

    #pragma unroll
    for (int p = 0; p < 3; ++p) {            // prologue: tiles 0,1,2 -> bufs 0,1,2
        const int d = p * 16384;
        GLL16(aS + p * 32,      &L[d + dA0]);
        GLL16(aS + p * 32 + 16, &L[d + dA1]);
        GLL16(bS + p * 32,      &L[d + dB0]);
        GLL16(bS + p * 32 + 16, &L[d + dB1]);
    }
    asm volatile("s_waitcnt vmcnt(8)" ::: "memory");   // tile 0 landed
    SBAR(); SCHED0();

    for (int kt = 0; kt < nk; ++kt) {
        const int bb = (kt & 3) * 16384;
        const int sb = ((kt + 3) & 3) * 16384;
        const u16* sa = aS + (kt + 3) * 32;
        const u16* sbp = bS + (kt + 3) * 32;
        const bool st = (kt + 3) < nk;

        // ---- phase A: row-frags 0-3, stage A(kt+3)
        bf16x8 aF[4], bF[4];
        #pragma unroll
        for (int i = 0; i < 4; ++i) aF[i] = *(const bf16x8*)&L[bb + rdA + i * 128];
        #pragma unroll
        for (int j = 0; j < 4; ++j) bF[j] = *(const bf16x8*)&L[bb + rdB + j * 128];
        if (st) { GLL16(sa, &L[sb + dA0]); GLL16(sa + 16, &L[sb + dA1]); }
        SBAR();
        __builtin_amdgcn_s_setprio(1);
        #pragma unroll
        for (int i = 0; i < 4; ++i)
            #pragma unroll
            for (int j = 0; j < 4; ++j)
                acc[i][j] = __builtin_amdgcn_mfma_f32_16x16x32_bf16(aF[i], bF[j], acc[i][j], 0, 0, 0);
        __builtin_amdgcn_s_setprio(0);
        SBAR();

        // ---- phase B: row-frags 4-7 (B frags reused in regs), stage B(kt+3)
        bf16x8 aG[4];
        #pragma unroll
        for (int i = 0; i < 4; ++i) aG[i] = *(const bf16x8*)&L[bb + rdA + 512 + i * 128];
        if (st) { GLL16(sbp, &L[sb + dB0]); GLL16(sbp + 16, &L[sb + dB1]); }
        SBAR();
        __builtin_amdgcn_s_setprio(1);
        #pragma unroll
        for (int i = 0; i < 4; ++i)
            #pragma unroll
            for (int j = 0; j < 4; ++j)
                acc[i + 4][j] = __builtin_amdgcn_mfma_f32_16x16x32_bf16(aG[i], bF[j], acc[i + 4][j], 0, 0, 0);
        __builtin_amdgcn_s_setprio(0);
        // publish tile kt+1 to all waves: counted in main loop, tail-exact at end
        if (kt + 3 < nk)      asm volatile("s_waitcnt vmcnt(8)" ::: "memory");
        else if (kt + 2 < nk) asm volatile("s_waitcnt vmcnt(4)" ::: "memory");
        else                  asm volatile("s_waitcnt vmcnt(0)" ::: "memory");
        SBAR(); SCHED0();
    }

    // epilogue: C/D map col = lane&15, row = (lane>>4)*4 + reg
    const size_t GM2 = (size_t)M << 11;
    #pragma unroll
    for (int i = 0; i < 8; ++i) {
        int r0 = m0 + wr * 128 + i * 16 + kq * 4;
        #pragma unroll
        for (int j = 0; j < 4; ++j) {
            int gc = n0 + wc * 64 + j * 16 + lr;
            float bv = bias[gc];
            int g = gc >> 11;
            bool sig = gateMode && (g == 1 || g == 2);
            size_t base = gateMode ? (size_t)g * GM2 + (size_t)(gc & 2047) : (size_t)gc;
            size_t rs = gateMode ? 2048 : (size_t)N;
            #pragma unroll
            for (int q = 0; q < 4; ++q) {
                float v = acc[i][j][q] + bv;
                if (sig) v = 1.f / (1.f + __expf(-v));
                out[base + (size_t)(r0 + q) * rs] = f2bf(v);
            }
        }
    }
}

// ---- SRU recurrence: one thread per (b,n) chain ----
__global__ void k_scan(const u16* __restrict__ G, const float* __restrict__ c0,
                       u16* __restrict__ hb, float* __restrict__ hf,
                       float* __restrict__ cout)
{
    int idx = blockIdx.x * 256 + threadIdx.x;  // 0..BB*NOUT-1
    int b = idx >> 11, n = idx & 2047;
    float c = c0[idx];
    const size_t GM = (size_t)MR * 2048;
    for (int t = 0; t < TT; ++t) {
        size_t p = ((size_t)(t * BB + b) << 11) + (size_t)n;
        float xp = bf2f(G[p]);
        float f  = bf2f(G[GM + p]);
        float r  = bf2f(G[2 * GM + p]);
        float cx = bf2f(G[3 * GM + p]);
        c = f * c + (1.f - f) * xp;
        float h = r * tanhf(c) + (1.f - r) * cx;
        if (hb) hb[p] = f2bf(h);
        if (hf) hf[p] = h;
    }
    if (cout) cout[idx] = c;
}

extern "C" void kernel_launch(void* const* d_in, const int* in_sizes, int n_in,
                              void* d_out, int out_size, void* d_ws, size_t ws_size,
                              hipStream_t stream)
{
    const float* xt  = (const float*)d_in[0];
    const float* ctf = (const float*)d_in[1];
    const float* Wx  = (const float*)d_in[2];
    const float* Wf  = (const float*)d_in[3];
    const float* bfp = (const float*)d_in[4];
    const float* Wr  = (const float*)d_in[5];
    const float* brp = (const float*)d_in[6];
    const float* Wcx = (const float*)d_in[7];
    const float* bcx = (const float*)d_in[8];
    const float* Wcl = (const float*)d_in[9];
    const float* bcl = (const float*)d_in[10];
    float* out = (float*)d_out;

    char* ws = (char*)d_ws;
    u16* x0 = (u16*)ws;       ws += (size_t)MR * NIN * 2;
    u16* x2 = (u16*)ws;       ws += (size_t)MR * NIN * 2;
    u16* h1 = (u16*)ws;       ws += (size_t)MR * NOUT * 2;
    u16* WTall = (u16*)ws;    ws += (size_t)4 * NOUT * NIN * 2;
    u16* WclT = (u16*)ws;     ws += (size_t)NIN * NOUT * 2;
    float* ball = (float*)ws; ws += (size_t)4 * NOUT * 4;
    u16* G = (u16*)ws;        ws += (size_t)4 * MR * NOUT * 2;

    dim3 tb(32, 8);
    k_cvt<<<2048, 256, 0, stream>>>(xt, x0, (MR * NIN) / 4);
    k_transpose<<<dim3(NOUT / 32, NIN / 32), tb, 0, stream>>>(Wx,  WTall + 0 * (size_t)NOUT * NIN, NIN, NOUT);
    k_transpose<<<dim3(NOUT / 32, NIN / 32), tb, 0, stream>>>(Wf,  WTall + 1 * (size_t)NOUT * NIN, NIN, NOUT);
    k_transpose<<<dim3(NOUT / 32, NIN / 32), tb, 0, stream>>>(Wr,  WTall + 2 * (size_t)NOUT * NIN, NIN, NOUT);
    k_transpose<<<dim3(NOUT / 32, NIN / 32), tb, 0, stream>>>(Wcx, WTall + 3 * (size_t)NOUT * NIN, NIN, NOUT);
    k_transpose<<<dim3(NIN / 32, NOUT / 32), tb, 0, stream>>>(Wcl, WclT, NOUT, NIN);
    k_bias_pack<<<32, 256, 0, stream>>>(bfp, brp, bcx, ball);

    // layer 1: fused 4-gate GEMM (N = 4*2048) + scan
    k_gemm256<<<dim3(4 * NOUT / 256, MR / 256), 512, 0, stream>>>(
        x0, WTall, ball, G, MR, 4 * NOUT, NIN, 1);
    k_scan<<<(BB * NOUT) / 256, 256, 0, stream>>>(
        G, ctf, h1, (float*)nullptr, (float*)nullptr);

    // inter-layer projection: x2 = h1 @ Wcl + bcl
    k_gemm256<<<dim3(NIN / 256, MR / 256), 512, 0, stream>>>(
        h1, WclT, bcl, x2, MR, NIN, NOUT, 0);

    // layer 2: gates + scan -> d_out (h2 f32 + c_last)
    k_gemm256<<<dim3(4 * NOUT / 256, MR / 256), 512, 0, stream>>>(
        x2, WTall, ball, G, MR, 4 * NOUT, NIN, 1);
    k_scan<<<(BB * NOUT) / 256, 256, 0, stream>>>(
        G, ctf + (size_t)BB * NOUT, (u16*)nullptr, out, out + (size_t)MR * NOUT);
}

// Round 3
// 512.842 us; speedup vs baseline: 1.2305x; 1.1958x over previous
//
#include <hip/hip_runtime.h>

#define TT 128
#define BB 64
#define NIN 1024
#define NOUT 2048
#define MR (TT*BB)   // 8192 rows (T*B)

typedef unsigned short u16;
typedef __attribute__((ext_vector_type(8))) __bf16 bf16x8;
typedef __attribute__((ext_vector_type(4))) float f32x4;
typedef __attribute__((ext_vector_type(8))) unsigned short u16x8;

static __device__ __forceinline__ u16 f2bf(float f) {
    union { float f; unsigned u; } v; v.f = f;
    unsigned r = v.u + 0x7fffu + ((v.u >> 16) & 1u);  // RNE
    return (u16)(r >> 16);
}
static __device__ __forceinline__ float bf2f(u16 x) {
    union { unsigned u; float f; } v; v.u = ((unsigned)x) << 16;
    return v.f;
}

// ---- x [M][K] f32 -> chunked bf16 [(K/8)][M][8] ----
__global__ void k_cvt_chunk(const float* __restrict__ s, u16* __restrict__ d, int M_, int K_) {
    __shared__ float t[64][33];
    int m0 = blockIdx.x * 64, k0 = blockIdx.y * 32;
    int ml = threadIdx.x >> 3, kl = (threadIdx.x & 7) * 4;
    #pragma unroll
    for (int p = 0; p < 2; ++p) {
        float4 v = *(const float4*)&s[(size_t)(m0 + ml + p * 32) * K_ + k0 + kl];
        t[ml + p * 32][kl] = v.x; t[ml + p * 32][kl + 1] = v.y;
        t[ml + p * 32][kl + 2] = v.z; t[ml + p * 32][kl + 3] = v.w;
    }
    __syncthreads();
    int q = threadIdx.x >> 6, row = threadIdx.x & 63;
    u16x8 o;
    #pragma unroll
    for (int j = 0; j < 8; ++j) o[j] = f2bf(t[row][q * 8 + j]);
    *(u16x8*)&d[(((size_t)(k0 >> 3) + q) * M_ + m0 + row) * 8] = o;
}

// ---- W [K][N] f32 -> chunked bf16 B^T [(K/8)][OUTM][8] at row offset ----
__global__ void k_wT_chunk(const float* __restrict__ s, u16* __restrict__ d,
                           int K_, int N_, int OUTM, int row_off) {
    __shared__ float t[32][65];
    int k0 = blockIdx.y * 32, n0 = blockIdx.x * 64;
    int kl = threadIdx.x >> 6, nl = threadIdx.x & 63;
    #pragma unroll
    for (int p = 0; p < 8; ++p)
        t[kl + p * 4][nl] = s[(size_t)(k0 + kl + p * 4) * N_ + n0 + nl];
    __syncthreads();
    int q = threadIdx.x >> 6, row = threadIdx.x & 63;
    u16x8 o;
    #pragma unroll
    for (int j = 0; j < 8; ++j) o[j] = f2bf(t[q * 8 + j][row]);
    *(u16x8*)&d[(((size_t)(k0 >> 3) + q) * OUTM + row_off + n0 + row) * 8] = o;
}

__global__ void k_bias_pack(const float* __restrict__ bf_, const float* __restrict__ br_,
                            const float* __restrict__ bcx_, float* __restrict__ ball) {
    int i = blockIdx.x * 256 + threadIdx.x;
    int g = i >> 11, n = i & 2047;
    float v = 0.f;
    if (g == 1) v = bf_[n];
    else if (g == 2) v = br_[n];
    else if (g == 3) v = bcx_[n];
    ball[i] = v;
}

#define GLL16(SRC, DST) __builtin_amdgcn_global_load_lds( \
    (const __attribute__((address_space(1))) void*)(SRC), \
    (__attribute__((address_space(3))) void*)(DST), 16, 0, 0)
#define SBAR() __builtin_amdgcn_s_barrier()
#define SCHED0() __builtin_amdgcn_sched_barrier(0)

// Chunked-layout GEMM. A [(K/8)][M][8], BT [(K/8)][NB][8] (both bf16 chunked).
// BM = WM*32 (256 or 128), BN = 256, BK = 32, 8 waves (wr = w>>2 in {0,1}, wc = w&3).
// LDS: 4-deep ring; per buffer A = BM*4 chunks then B = 1024 chunks of 16B,
// chunk (q,row) at index q*ROWS+row -> consecutive chunks = consecutive rows:
// zero-conflict frag reads AND contiguous 1KB global wave-loads.
template<int WM>
__global__ __launch_bounds__(512) void k_gemm_c(
    const u16* __restrict__ A, const u16* __restrict__ BT,
    const float* __restrict__ bias, u16* __restrict__ outG, u16* __restrict__ outC,
    int M, int NB, int K)
{
    constexpr int BM = WM * 32;
    constexpr int BUF = BM * 32 + 8192;      // elems per ring slot
    constexpr int AL = (WM == 8) ? 2 : 1;    // A gll per thread per tile
    __shared__ __align__(16) u16 L[4 * BUF];

    const int tid = threadIdx.x;
    const int w = tid >> 6, lane = tid & 63;
    const int wr = w >> 2, wc = w & 3;
    const int lr = lane & 15, kq = lane >> 4;
    const int m0 = blockIdx.y * BM, n0 = blockIdx.x * 256;
    const int nk = K >> 5;

    // staging: A chunks tc = tid + l*512 -> (q = tc/BM, row = tc%BM); B same with 256 rows.
    const u16* aSrc[AL]; int aDst[AL];
    #pragma unroll
    for (int l = 0; l < AL; ++l) {
        int tc = tid + l * 512;
        int q = tc / BM, row = tc % BM;
        aSrc[l] = A + ((size_t)q * M + m0 + row) * 8;
        aDst[l] = (w * 64 + l * 512) * 8;
    }
    const u16* bSrc[2]; int bDst[2];
    #pragma unroll
    for (int l = 0; l < 2; ++l) {
        int tc = tid + l * 512;
        int q = tc >> 8, row = tc & 255;
        bSrc[l] = BT + ((size_t)q * NB + n0 + row) * 8;
        bDst[l] = BM * 32 + (w * 64 + l * 512) * 8;
    }
    const size_t aStep = (size_t)32 * M;     // elems per K-tile in chunked A
    const size_t bStep = (size_t)32 * NB;

    const int rdA = wr * (WM * 16) + lr;     // A frag row base
    const int rdB = wc * 64 + lr;

    f32x4 acc[WM][4] = {};

    #pragma unroll
    for (int p = 0; p < 3; ++p) {            // prologue: tiles 0,1,2 -> bufs 0,1,2
        #pragma unroll
        for (int l = 0; l < AL; ++l) GLL16(aSrc[l] + (size_t)p * aStep, &L[p * BUF + aDst[l]]);
        #pragma unroll
        for (int l = 0; l < 2; ++l)  GLL16(bSrc[l] + (size_t)p * bStep, &L[p * BUF + bDst[l]]);
    }
    if (WM == 8) asm volatile("s_waitcnt vmcnt(8)" ::: "memory");
    else         asm volatile("s_waitcnt vmcnt(6)" ::: "memory");
    SBAR(); SCHED0();

    for (int kt = 0; kt < nk; ++kt) {
        const int bb = (kt & 3) * BUF;
        const int sb = ((kt + 3) & 3) * BUF;
        const bool st = (kt + 3) < nk;
        const size_t sOffA = (size_t)(kt + 3) * aStep;
        const size_t sOffB = (size_t)(kt + 3) * bStep;

        bf16x8 aF[4], bF[4];
        #pragma unroll
        for (int i = 0; i < 4; ++i)
            aF[i] = *(const bf16x8*)&L[bb + (kq * BM + rdA + i * 16) * 8];
        #pragma unroll
        for (int j = 0; j < 4; ++j)
            bF[j] = *(const bf16x8*)&L[bb + BM * 32 + (kq * 256 + rdB + j * 16) * 8];
        if (st) {
            #pragma unroll
            for (int l = 0; l < AL; ++l) GLL16(aSrc[l] + sOffA, &L[sb + aDst[l]]);
        }
        SBAR();
        __builtin_amdgcn_s_setprio(1);
        #pragma unroll
        for (int i = 0; i < 4; ++i)
            #pragma unroll
            for (int j = 0; j < 4; ++j)
                acc[i][j] = __builtin_amdgcn_mfma_f32_16x16x32_bf16(aF[i], bF[j], acc[i][j], 0, 0, 0);
        __builtin_amdgcn_s_setprio(0);

        if constexpr (WM == 8) {
            SBAR();
            bf16x8 aG[4];
            #pragma unroll
            for (int i = 0; i < 4; ++i)
                aG[i] = *(const bf16x8*)&L[bb + (kq * BM + rdA + 64 + i * 16) * 8];
            if (st) {
                #pragma unroll
                for (int l = 0; l < 2; ++l) GLL16(bSrc[l] + sOffB, &L[sb + bDst[l]]);
            }
            SBAR();
            __builtin_amdgcn_s_setprio(1);
            #pragma unroll
            for (int i = 0; i < 4; ++i)
                #pragma unroll
                for (int j = 0; j < 4; ++j)
                    acc[i + 4][j] = __builtin_amdgcn_mfma_f32_16x16x32_bf16(aG[i], bF[j], acc[i + 4][j], 0, 0, 0);
            __builtin_amdgcn_s_setprio(0);
            if (kt + 3 < nk)      asm volatile("s_waitcnt vmcnt(8)" ::: "memory");
            else if (kt + 2 < nk) asm volatile("s_waitcnt vmcnt(4)" ::: "memory");
            else                  asm volatile("s_waitcnt vmcnt(0)" ::: "memory");
        } else {
            if (st) {
                #pragma unroll
                for (int l = 0; l < 2; ++l) GLL16(bSrc[l] + sOffB, &L[sb + bDst[l]]);
            }
            if (kt + 3 < nk)      asm volatile("s_waitcnt vmcnt(6)" ::: "memory");
            else if (kt + 2 < nk) asm volatile("s_waitcnt vmcnt(3)" ::: "memory");
            else                  asm volatile("s_waitcnt vmcnt(0)" ::: "memory");
        }
        SBAR(); SCHED0();
    }

    // epilogue: C/D map col = lane&15, row = (lane>>4)*4 + reg
    const size_t GM2 = (size_t)M << 11;
    #pragma unroll
    for (int i = 0; i < WM; ++i) {
        int r0 = m0 + wr * (WM * 16) + i * 16 + kq * 4;
        #pragma unroll
        for (int j = 0; j < 4; ++j) {
            int gc = n0 + wc * 64 + j * 16 + lr;
            float bv = bias[gc];
            if (outG) {  // gates [4][M][2048], sigmoid on g=1,2
                int g = gc >> 11;
                bool sig = (g == 1 || g == 2);
                size_t base = (size_t)g * GM2 + (size_t)(gc & 2047);
                #pragma unroll
                for (int q = 0; q < 4; ++q) {
                    float v = acc[i][j][q] + bv;
                    if (sig) v = 1.f / (1.f + __expf(-v));
                    outG[base + (size_t)(r0 + q) * 2048] = f2bf(v);
                }
            } else {     // chunked x2: ((gc>>3)*M + r)*8 + (gc&7)
                size_t base = ((size_t)(gc >> 3) * M) * 8 + (size_t)(gc & 7);
                #pragma unroll
                for (int q = 0; q < 4; ++q)
                    outC[base + (size_t)(r0 + q) * 8] = f2bf(acc[i][j][q] + bv);
            }
        }
    }
}

// ---- SRU recurrence: one thread per (b,n) chain; hb (if set) written CHUNKED ----
__global__ void k_scan(const u16* __restrict__ G, const float* __restrict__ c0,
                       u16* __restrict__ hb, float* __restrict__ hf,
                       float* __restrict__ cout)
{
    int idx = blockIdx.x * 256 + threadIdx.x;
    int b = idx >> 11, n = idx & 2047;
    float c = c0[idx];
    const size_t GM = (size_t)MR * 2048;
    const size_t hcBase = ((size_t)(n >> 3) * MR) * 8 + (size_t)(n & 7);
    for (int t = 0; t < TT; ++t) {
        int m = t * BB + b;
        size_t p = ((size_t)m << 11) + (size_t)n;
        float xp = bf2f(G[p]);
        float f  = bf2f(G[GM + p]);
        float r  = bf2f(G[2 * GM + p]);
        float cx = bf2f(G[3 * GM + p]);
        c = f * c + (1.f - f) * xp;
        float h = r * tanhf(c) + (1.f - r) * cx;
        if (hb) hb[hcBase + (size_t)m * 8] = f2bf(h);
        if (hf) hf[p] = h;
    }
    if (cout) cout[idx] = c;
}

extern "C" void kernel_launch(void* const* d_in, const int* in_sizes, int n_in,
                              void* d_out, int out_size, void* d_ws, size_t ws_size,
                              hipStream_t stream)
{
    const float* xt  = (const float*)d_in[0];
    const float* ctf = (const float*)d_in[1];
    const float* Wx  = (const float*)d_in[2];
    const float* Wf  = (const float*)d_in[3];
    const float* bfp = (const float*)d_in[4];
    const float* Wr  = (const float*)d_in[5];
    const float* brp = (const float*)d_in[6];
    const float* Wcx = (const float*)d_in[7];
    const float* bcx = (const float*)d_in[8];
    const float* Wcl = (const float*)d_in[9];
    const float* bcl = (const float*)d_in[10];
    float* out = (float*)d_out;

    char* ws = (char*)d_ws;
    u16* x0 = (u16*)ws;       ws += (size_t)MR * NIN * 2;        // chunked [(1024/8)][8192][8]
    u16* x2 = (u16*)ws;       ws += (size_t)MR * NIN * 2;        // chunked
    u16* h1 = (u16*)ws;       ws += (size_t)MR * NOUT * 2;       // chunked [(2048/8)][8192][8]
    u16* WTall = (u16*)ws;    ws += (size_t)4 * NOUT * NIN * 2;  // chunked [(1024/8)][8192][8]
    u16* WclT = (u16*)ws;     ws += (size_t)NIN * NOUT * 2;      // chunked [(2048/8)][1024][8]
    float* ball = (float*)ws; ws += (size_t)4 * NOUT * 4;
    u16* G = (u16*)ws;        ws += (size_t)4 * MR * NOUT * 2;   // [4][8192][2048]

    k_cvt_chunk<<<dim3(MR / 64, NIN / 32), 256, 0, stream>>>(xt, x0, MR, NIN);
    k_wT_chunk<<<dim3(NOUT / 64, NIN / 32), 256, 0, stream>>>(Wx,  WTall, NIN, NOUT, 4 * NOUT, 0 * NOUT);
    k_wT_chunk<<<dim3(NOUT / 64, NIN / 32), 256, 0, stream>>>(Wf,  WTall, NIN, NOUT, 4 * NOUT, 1 * NOUT);
    k_wT_chunk<<<dim3(NOUT / 64, NIN / 32), 256, 0, stream>>>(Wr,  WTall, NIN, NOUT, 4 * NOUT, 2 * NOUT);
    k_wT_chunk<<<dim3(NOUT / 64, NIN / 32), 256, 0, stream>>>(Wcx, WTall, NIN, NOUT, 4 * NOUT, 3 * NOUT);
    k_wT_chunk<<<dim3(NIN / 64, NOUT / 32), 256, 0, stream>>>(Wcl, WclT, NOUT, NIN, NIN, 0);
    k_bias_pack<<<32, 256, 0, stream>>>(bfp, brp, bcx, ball);

    // layer 1: fused 4-gate GEMM (NB = 8192) + scan (h1 chunked)
    k_gemm_c<8><<<dim3(32, 32), 512, 0, stream>>>(x0, WTall, ball, G, (u16*)nullptr, MR, 4 * NOUT, NIN);
    k_scan<<<(BB * NOUT) / 256, 256, 0, stream>>>(G, ctf, h1, (float*)nullptr, (float*)nullptr);

    // inter-layer projection: x2 = h1 @ Wcl + bcl  (BM=128 -> 256 blocks)
    k_gemm_c<4><<<dim3(NIN / 256, MR / 128), 512, 0, stream>>>(h1, WclT, bcl, (u16*)nullptr, x2, MR, NIN, NOUT);

    // layer 2: gates + scan -> d_out (h2 f32 + c_last)
    k_gemm_c<8><<<dim3(32, 32), 512, 0, stream>>>(x2, WTall, ball, G, (u16*)nullptr, MR, 4 * NOUT, NIN);
    k_scan<<<(BB * NOUT) / 256, 256, 0, stream>>>(G, ctf + (size_t)BB * NOUT, (u16*)nullptr, out, out + (size_t)MR * NOUT);
}

// Round 4
// 470.234 us; speedup vs baseline: 1.3420x; 1.0906x over previous
//
#include <hip/hip_runtime.h>

#define TT 128
#define BB 64
#define NIN 1024
#define NOUT 2048
#define MR (TT*BB)   // 8192 rows (T*B)

typedef unsigned short u16;
typedef __attribute__((ext_vector_type(8))) __bf16 bf16x8;
typedef __attribute__((ext_vector_type(4))) float f32x4;
typedef __attribute__((ext_vector_type(8))) unsigned short u16x8;

static __device__ __forceinline__ u16 f2bf(float f) {
    union { float f; unsigned u; } v; v.f = f;
    unsigned r = v.u + 0x7fffu + ((v.u >> 16) & 1u);  // RNE
    return (u16)(r >> 16);
}
static __device__ __forceinline__ float bf2f(u16 x) {
    union { unsigned u; float f; } v; v.u = ((unsigned)x) << 16;
    return v.f;
}

// ---- x [M][K] f32 -> chunked bf16 [(K/8)][M][8] ----
__global__ void k_cvt_chunk(const float* __restrict__ s, u16* __restrict__ d, int M_, int K_) {
    __shared__ float t[64][33];
    int m0 = blockIdx.x * 64, k0 = blockIdx.y * 32;
    int ml = threadIdx.x >> 3, kl = (threadIdx.x & 7) * 4;
    #pragma unroll
    for (int p = 0; p < 2; ++p) {
        float4 v = *(const float4*)&s[(size_t)(m0 + ml + p * 32) * K_ + k0 + kl];
        t[ml + p * 32][kl] = v.x; t[ml + p * 32][kl + 1] = v.y;
        t[ml + p * 32][kl + 2] = v.z; t[ml + p * 32][kl + 3] = v.w;
    }
    __syncthreads();
    int q = threadIdx.x >> 6, row = threadIdx.x & 63;
    u16x8 o;
    #pragma unroll
    for (int j = 0; j < 8; ++j) o[j] = f2bf(t[row][q * 8 + j]);
    *(u16x8*)&d[(((size_t)(k0 >> 3) + q) * M_ + m0 + row) * 8] = o;
}

// ---- W [K][N] f32 -> chunked bf16 B^T [(K/8)][OUTM][8] at row offset ----
__global__ void k_wT_chunk(const float* __restrict__ s, u16* __restrict__ d,
                           int K_, int N_, int OUTM, int row_off) {
    __shared__ float t[32][65];
    int k0 = blockIdx.y * 32, n0 = blockIdx.x * 64;
    int kl = threadIdx.x >> 6, nl = threadIdx.x & 63;
    #pragma unroll
    for (int p = 0; p < 8; ++p)
        t[kl + p * 4][nl] = s[(size_t)(k0 + kl + p * 4) * N_ + n0 + nl];
    __syncthreads();
    int q = threadIdx.x >> 6, row = threadIdx.x & 63;
    u16x8 o;
    #pragma unroll
    for (int j = 0; j < 8; ++j) o[j] = f2bf(t[q * 8 + j][row]);
    *(u16x8*)&d[(((size_t)(k0 >> 3) + q) * OUTM + row_off + n0 + row) * 8] = o;
}

__global__ void k_bias_pack(const float* __restrict__ bf_, const float* __restrict__ br_,
                            const float* __restrict__ bcx_, float* __restrict__ ball) {
    int i = blockIdx.x * 256 + threadIdx.x;
    int g = i >> 11, n = i & 2047;
    float v = 0.f;
    if (g == 1) v = bf_[n];
    else if (g == 2) v = br_[n];
    else if (g == 3) v = bcx_[n];
    ball[i] = v;
}

#define GLL16(SRC, DST) __builtin_amdgcn_global_load_lds( \
    (const __attribute__((address_space(1))) void*)(SRC), \
    (__attribute__((address_space(3))) void*)(DST), 16, 0, 0)
#define SBAR() __builtin_amdgcn_s_barrier()
#define SCHED0() __builtin_amdgcn_sched_barrier(0)

// ============ gate GEMM: BM=256, BN=256, BK=32, 8 waves, 4-deep ring ============
// A [(K/8)][M][8], BT [(K/8)][8192][8] chunked bf16. One barrier per K-tile;
// register-pipelined frags (ping-pong sets), publication 2 tiles ahead (vmcnt(4)).
__global__ __launch_bounds__(512, 2) void k_gemm8(
    const u16* __restrict__ A, const u16* __restrict__ BT,
    const float* __restrict__ bias, u16* __restrict__ outG,
    int M, int NB, int K)
{
    constexpr int BM = 256;
    constexpr int BUF = BM * 32 + 8192;
    __shared__ __align__(16) u16 L[4 * BUF];

    const int tid = threadIdx.x;
    const int w = tid >> 6, lane = tid & 63;
    const int wr = w >> 2, wc = w & 3;
    const int lr = lane & 15, kq = lane >> 4;
    // XCD-aware swizzle (grid is 32x32 = 1024, %8 == 0)
    const int gx = gridDim.x;
    const int nwg = gx * gridDim.y;
    const int flat = blockIdx.y * gx + blockIdx.x;
    const int swz = (flat & 7) * (nwg >> 3) + (flat >> 3);
    const int m0 = (swz / gx) * BM, n0 = (swz % gx) * 256;
    const int nk = K >> 5;

    const u16* aSrc[2]; int aDst[2];
    #pragma unroll
    for (int l = 0; l < 2; ++l) {
        int tc = tid + l * 512;
        aSrc[l] = A + ((size_t)(tc >> 8) * M + m0 + (tc & 255)) * 8;
        aDst[l] = (w * 64 + l * 512) * 8;
    }
    const u16* bSrc[2]; int bDst[2];
    #pragma unroll
    for (int l = 0; l < 2; ++l) {
        int tc = tid + l * 512;
        bSrc[l] = BT + ((size_t)(tc >> 8) * NB + n0 + (tc & 255)) * 8;
        bDst[l] = BM * 32 + (w * 64 + l * 512) * 8;
    }
    const size_t aStep = (size_t)32 * M;
    const size_t bStep = (size_t)32 * NB;
    const int rdA = wr * 128 + lr;
    const int rdB = wc * 64 + lr;

    f32x4 acc[8][4] = {};
    bf16x8 aP0[4], bP0[4], aP1[4], bP1[4];

    #pragma unroll
    for (int p = 0; p < 3; ++p) {
        #pragma unroll
        for (int l = 0; l < 2; ++l) GLL16(aSrc[l] + (size_t)p * aStep, &L[p * BUF + aDst[l]]);
        #pragma unroll
        for (int l = 0; l < 2; ++l) GLL16(bSrc[l] + (size_t)p * bStep, &L[p * BUF + bDst[l]]);
    }
    asm volatile("s_waitcnt vmcnt(4)" ::: "memory");  // tiles 0,1 resident
    SBAR(); SCHED0();
    #pragma unroll
    for (int i = 0; i < 4; ++i) aP0[i] = *(const bf16x8*)&L[(kq * BM + rdA + i * 16) * 8];
    #pragma unroll
    for (int j = 0; j < 4; ++j) bP0[j] = *(const bf16x8*)&L[BM * 32 + (kq * 256 + rdB + j * 16) * 8];

#define ITER8(KT, CUR, NXT) { \
    const int kt_ = (KT); \
    const int bb = (kt_ & 3) * BUF; \
    const int tn = (kt_ + 1 < nk) ? kt_ + 1 : nk - 1; \
    const int nb = (tn & 3) * BUF; \
    bf16x8 aG[4]; \
    _Pragma("unroll") for (int i = 0; i < 4; ++i) \
        aG[i] = *(const bf16x8*)&L[bb + (kq * BM + rdA + 64 + i * 16) * 8]; \
    if (kt_ + 3 < nk) { \
        const size_t sa = (size_t)(kt_ + 3) * aStep, sb_ = (size_t)(kt_ + 3) * bStep; \
        const int wb = ((kt_ + 3) & 3) * BUF; \
        _Pragma("unroll") for (int l = 0; l < 2; ++l) GLL16(aSrc[l] + sa, &L[wb + aDst[l]]); \
        _Pragma("unroll") for (int l = 0; l < 2; ++l) GLL16(bSrc[l] + sb_, &L[wb + bDst[l]]); \
    } \
    __builtin_amdgcn_s_setprio(1); \
    _Pragma("unroll") for (int i = 0; i < 4; ++i) \
        _Pragma("unroll") for (int j = 0; j < 4; ++j) \
            acc[i][j] = __builtin_amdgcn_mfma_f32_16x16x32_bf16(aP##CUR[i], bP##CUR[j], acc[i][j], 0, 0, 0); \
    _Pragma("unroll") for (int i = 0; i < 4; ++i) \
        aP##NXT[i] = *(const bf16x8*)&L[nb + (kq * BM + rdA + i * 16) * 8]; \
    _Pragma("unroll") for (int j = 0; j < 4; ++j) \
        bP##NXT[j] = *(const bf16x8*)&L[nb + BM * 32 + (kq * 256 + rdB + j * 16) * 8]; \
    _Pragma("unroll") for (int i = 0; i < 4; ++i) \
        _Pragma("unroll") for (int j = 0; j < 4; ++j) \
            acc[i + 4][j] = __builtin_amdgcn_mfma_f32_16x16x32_bf16(aG[i], bP##CUR[j], acc[i + 4][j], 0, 0, 0); \
    __builtin_amdgcn_s_setprio(0); \
    asm volatile("s_waitcnt vmcnt(4)" ::: "memory"); \
    SBAR(); SCHED0(); }

    for (int kt4 = 0; kt4 < nk; kt4 += 4) {
        ITER8(kt4 + 0, 0, 1);
        ITER8(kt4 + 1, 1, 0);
        ITER8(kt4 + 2, 0, 1);
        ITER8(kt4 + 3, 1, 0);
    }
#undef ITER8

    // epilogue: gates [4][M][2048], sigmoid on g=1,2
    const size_t GM2 = (size_t)M << 11;
    #pragma unroll
    for (int i = 0; i < 8; ++i) {
        int r0 = m0 + wr * 128 + i * 16 + kq * 4;
        #pragma unroll
        for (int j = 0; j < 4; ++j) {
            int gc = n0 + wc * 64 + j * 16 + lr;
            float bv = bias[gc];
            int g = gc >> 11;
            bool sig = (g == 1 || g == 2);
            size_t base = (size_t)g * GM2 + (size_t)(gc & 2047);
            #pragma unroll
            for (int q = 0; q < 4; ++q) {
                float v = acc[i][j][q] + bv;
                if (sig) v = 1.f / (1.f + __expf(-v));
                outG[base + (size_t)(r0 + q) * 2048] = f2bf(v);
            }
        }
    }
}

// ============ projection GEMM: BM=128, BN=256, 8 waves (wave tile 64x64) ============
__global__ __launch_bounds__(512, 2) void k_gemm4(
    const u16* __restrict__ A, const u16* __restrict__ BT,
    const float* __restrict__ bias, u16* __restrict__ outC,
    int M, int NB, int K)
{
    constexpr int BM = 128;
    constexpr int BUF = BM * 32 + 8192;
    __shared__ __align__(16) u16 L[4 * BUF];

    const int tid = threadIdx.x;
    const int w = tid >> 6, lane = tid & 63;
    const int wr = w >> 2, wc = w & 3;
    const int lr = lane & 15, kq = lane >> 4;
    const int gx = gridDim.x;
    const int nwg = gx * gridDim.y;
    const int flat = blockIdx.y * gx + blockIdx.x;
    const int swz = (flat & 7) * (nwg >> 3) + (flat >> 3);
    const int m0 = (swz / gx) * BM, n0 = (swz % gx) * 256;
    const int nk = K >> 5;

    const u16* aSrc1; int aDst1;
    {
        int q = tid >> 7, row = tid & 127;
        aSrc1 = A + ((size_t)q * M + m0 + row) * 8;
        aDst1 = (w * 64) * 8;  // chunk index == tid -> linear
    }
    const u16* bSrc[2]; int bDst[2];
    #pragma unroll
    for (int l = 0; l < 2; ++l) {
        int tc = tid + l * 512;
        bSrc[l] = BT + ((size_t)(tc >> 8) * NB + n0 + (tc & 255)) * 8;
        bDst[l] = BM * 32 + (w * 64 + l * 512) * 8;
    }
    const size_t aStep = (size_t)32 * M;
    const size_t bStep = (size_t)32 * NB;
    const int rdA = wr * 64 + lr;
    const int rdB = wc * 64 + lr;

    f32x4 acc[4][4] = {};
    bf16x8 aP0[4], bP0[4], aP1[4], bP1[4];

    #pragma unroll
    for (int p = 0; p < 3; ++p) {
        GLL16(aSrc1 + (size_t)p * aStep, &L[p * BUF + aDst1]);
        #pragma unroll
        for (int l = 0; l < 2; ++l) GLL16(bSrc[l] + (size_t)p * bStep, &L[p * BUF + bDst[l]]);
    }
    asm volatile("s_waitcnt vmcnt(3)" ::: "memory");
    SBAR(); SCHED0();
    #pragma unroll
    for (int i = 0; i < 4; ++i) aP0[i] = *(const bf16x8*)&L[(kq * BM + rdA + i * 16) * 8];
    #pragma unroll
    for (int j = 0; j < 4; ++j) bP0[j] = *(const bf16x8*)&L[BM * 32 + (kq * 256 + rdB + j * 16) * 8];

#define ITER4(KT, CUR, NXT) { \
    const int kt_ = (KT); \
    const int tn = (kt_ + 1 < nk) ? kt_ + 1 : nk - 1; \
    const int nb = (tn & 3) * BUF; \
    if (kt_ + 3 < nk) { \
        const size_t sa = (size_t)(kt_ + 3) * aStep, sb_ = (size_t)(kt_ + 3) * bStep; \
        const int wb = ((kt_ + 3) & 3) * BUF; \
        GLL16(aSrc1 + sa, &L[wb + aDst1]); \
        _Pragma("unroll") for (int l = 0; l < 2; ++l) GLL16(bSrc[l] + sb_, &L[wb + bDst[l]]); \
    } \
    __builtin_amdgcn_s_setprio(1); \
    _Pragma("unroll") for (int i = 0; i < 4; ++i) \
        _Pragma("unroll") for (int j = 0; j < 4; ++j) \
            acc[i][j] = __builtin_amdgcn_mfma_f32_16x16x32_bf16(aP##CUR[i], bP##CUR[j], acc[i][j], 0, 0, 0); \
    _Pragma("unroll") for (int i = 0; i < 4; ++i) \
        aP##NXT[i] = *(const bf16x8*)&L[nb + (kq * BM + rdA + i * 16) * 8]; \
    _Pragma("unroll") for (int j = 0; j < 4; ++j) \
        bP##NXT[j] = *(const bf16x8*)&L[nb + BM * 32 + (kq * 256 + rdB + j * 16) * 8]; \
    __builtin_amdgcn_s_setprio(0); \
    asm volatile("s_waitcnt vmcnt(3)" ::: "memory"); \
    SBAR(); SCHED0(); }

    for (int kt4 = 0; kt4 < nk; kt4 += 4) {
        ITER4(kt4 + 0, 0, 1);
        ITER4(kt4 + 1, 1, 0);
        ITER4(kt4 + 2, 0, 1);
        ITER4(kt4 + 3, 1, 0);
    }
#undef ITER4

    // epilogue: chunked x2 out: ((gc>>3)*M + r)*8 + (gc&7)
    #pragma unroll
    for (int i = 0; i < 4; ++i) {
        int r0 = m0 + wr * 64 + i * 16 + kq * 4;
        #pragma unroll
        for (int j = 0; j < 4; ++j) {
            int gc = n0 + wc * 64 + j * 16 + lr;
            float bv = bias[gc];
            size_t base = ((size_t)(gc >> 3) * M) * 8 + (size_t)(gc & 7);
            #pragma unroll
            for (int q = 0; q < 4; ++q)
                outC[base + (size_t)(r0 + q) * 8] = f2bf(acc[i][j][q] + bv);
        }
    }
}

// ---- SRU recurrence: one thread per (b,n) chain; hb (if set) written CHUNKED ----
__global__ void k_scan(const u16* __restrict__ G, const float* __restrict__ c0,
                       u16* __restrict__ hb, float* __restrict__ hf,
                       float* __restrict__ cout)
{
    int idx = blockIdx.x * 256 + threadIdx.x;
    int b = idx >> 11, n = idx & 2047;
    float c = c0[idx];
    const size_t GM = (size_t)MR * 2048;
    const size_t hcBase = ((size_t)(n >> 3) * MR) * 8 + (size_t)(n & 7);
    for (int t = 0; t < TT; ++t) {
        int m = t * BB + b;
        size_t p = ((size_t)m << 11) + (size_t)n;
        float xp = bf2f(G[p]);
        float f  = bf2f(G[GM + p]);
        float r  = bf2f(G[2 * GM + p]);
        float cx = bf2f(G[3 * GM + p]);
        c = f * c + (1.f - f) * xp;
        float h = r * tanhf(c) + (1.f - r) * cx;
        if (hb) hb[hcBase + (size_t)m * 8] = f2bf(h);
        if (hf) hf[p] = h;
    }
    if (cout) cout[idx] = c;
}

extern "C" void kernel_launch(void* const* d_in, const int* in_sizes, int n_in,
                              void* d_out, int out_size, void* d_ws, size_t ws_size,
                              hipStream_t stream)
{
    const float* xt  = (const float*)d_in[0];
    const float* ctf = (const float*)d_in[1];
    const float* Wx  = (const float*)d_in[2];
    const float* Wf  = (const float*)d_in[3];
    const float* bfp = (const float*)d_in[4];
    const float* Wr  = (const float*)d_in[5];
    const float* brp = (const float*)d_in[6];
    const float* Wcx = (const float*)d_in[7];
    const float* bcx = (const float*)d_in[8];
    const float* Wcl = (const float*)d_in[9];
    const float* bcl = (const float*)d_in[10];
    float* out = (float*)d_out;

    char* ws = (char*)d_ws;
    u16* x0 = (u16*)ws;       ws += (size_t)MR * NIN * 2;        // chunked
    u16* x2 = (u16*)ws;       ws += (size_t)MR * NIN * 2;        // chunked
    u16* h1 = (u16*)ws;       ws += (size_t)MR * NOUT * 2;       // chunked
    u16* WTall = (u16*)ws;    ws += (size_t)4 * NOUT * NIN * 2;  // chunked
    u16* WclT = (u16*)ws;     ws += (size_t)NIN * NOUT * 2;      // chunked
    float* ball = (float*)ws; ws += (size_t)4 * NOUT * 4;
    u16* G = (u16*)ws;        ws += (size_t)4 * MR * NOUT * 2;   // [4][8192][2048]

    k_cvt_chunk<<<dim3(MR / 64, NIN / 32), 256, 0, stream>>>(xt, x0, MR, NIN);
    k_wT_chunk<<<dim3(NOUT / 64, NIN / 32), 256, 0, stream>>>(Wx,  WTall, NIN, NOUT, 4 * NOUT, 0 * NOUT);
    k_wT_chunk<<<dim3(NOUT / 64, NIN / 32), 256, 0, stream>>>(Wf,  WTall, NIN, NOUT, 4 * NOUT, 1 * NOUT);
    k_wT_chunk<<<dim3(NOUT / 64, NIN / 32), 256, 0, stream>>>(Wr,  WTall, NIN, NOUT, 4 * NOUT, 2 * NOUT);
    k_wT_chunk<<<dim3(NOUT / 64, NIN / 32), 256, 0, stream>>>(Wcx, WTall, NIN, NOUT, 4 * NOUT, 3 * NOUT);
    k_wT_chunk<<<dim3(NIN / 64, NOUT / 32), 256, 0, stream>>>(Wcl, WclT, NOUT, NIN, NIN, 0);
    k_bias_pack<<<32, 256, 0, stream>>>(bfp, brp, bcx, ball);

    // layer 1: fused 4-gate GEMM (NB = 8192) + scan (h1 chunked)
    k_gemm8<<<dim3(32, 32), 512, 0, stream>>>(x0, WTall, ball, G, MR, 4 * NOUT, NIN);
    k_scan<<<(BB * NOUT) / 256, 256, 0, stream>>>(G, ctf, h1, (float*)nullptr, (float*)nullptr);

    // inter-layer projection: x2 = h1 @ Wcl + bcl  (grid 4 x 64 = 256)
    k_gemm4<<<dim3(NIN / 256, MR / 128), 512, 0, stream>>>(h1, WclT, bcl, x2, MR, NIN, NOUT);

    // layer 2: gates + scan -> d_out (h2 f32 + c_last)
    k_gemm8<<<dim3(32, 32), 512, 0, stream>>>(x2, WTall, ball, G, MR, 4 * NOUT, NIN);
    k_scan<<<(BB * NOUT) / 256, 256, 0, stream>>>(G, ctf + (size_t)BB * NOUT, (u16*)nullptr, out, out + (size_t)MR * NOUT);
}